// Round 15
// baseline (625.292 us; speedup 1.0000x reference)
//
#include <hip/hip_runtime.h>
#include <stdint.h>

typedef __bf16 bf16;
typedef __bf16 bf16x4 __attribute__((ext_vector_type(4)));
typedef __bf16 bf16x8 __attribute__((ext_vector_type(8)));
typedef float f32x4 __attribute__((ext_vector_type(4)));

#define GAS __attribute__((address_space(1)))
#define LAS __attribute__((address_space(3)))

__device__ __forceinline__ void gload_lds16(const void* g, void* l) {
  __builtin_amdgcn_global_load_lds((GAS const void*)g, (LAS void*)l, 16, 0, 0);
}

// ---------------- fp32 -> bf16 convert (x) ----------------
__global__ __launch_bounds__(256) void cvt_bf16(const float* __restrict__ in,
                                                bf16* __restrict__ out, int n4) {
  int i = blockIdx.x * 256 + threadIdx.x;
  if (i >= n4) return;
  float4 v = ((const float4*)in)[i];
  bf16x4 o;
  o[0] = (bf16)v.x; o[1] = (bf16)v.y; o[2] = (bf16)v.z; o[3] = (bf16)v.w;
  ((bf16x4*)out)[i] = o;
}

// ------------- W[K][N] f32 -> Wt[N][K] bf16 (transpose+convert) -------------
// Vectorized: float2 reads (8B/lane), bf16x4 writes (8B/lane, coalesced).
__global__ __launch_bounds__(256) void tconv(const float* __restrict__ W,
                                             bf16* __restrict__ Wt, int K, int N) {
  __shared__ bf16 tile[64][68];
  const int n0 = blockIdx.x * 64, k0 = blockIdx.y * 64;
  const int u2 = threadIdx.x & 31, kr0 = threadIdx.x >> 5;  // 32 n-pairs x 8 k-rows
#pragma unroll
  for (int i = 0; i < 8; ++i) {
    int kr = kr0 + i * 8;
    float2 v = *(const float2*)&W[(size_t)(k0 + kr) * N + n0 + u2 * 2];
    tile[kr][u2 * 2] = (bf16)v.x;
    tile[kr][u2 * 2 + 1] = (bf16)v.y;
  }
  __syncthreads();
  const int u4 = threadIdx.x & 15, nr0 = threadIdx.x >> 4;  // 16 k-quads x 16 n-rows
#pragma unroll
  for (int i = 0; i < 4; ++i) {
    int nr = nr0 + i * 16;
    bf16x4 o;
#pragma unroll
    for (int j = 0; j < 4; ++j) o[j] = tile[u4 * 4 + j][nr];
    *(bf16x4*)&Wt[(size_t)(n0 + nr) * K + k0 + u4 * 4] = o;
  }
}

// ============ 256x256 bf16 GEMM, depth-4 half-tile pipeline ============
// BK=64 as 2 kh-halves; LDS = 5 half-buffers[A 8192 | B 8192] = 160 KiB (full
// pool; occupancy unchanged at 1 block/CU). Half H uses a rolling buffer; its
// loads were issued 4 halves (~1240cy) earlier -> covers HBM latency (~900cy)
// plus jitter. Steady state: 16 loads in flight, vmcnt(12) per boundary,
// 1 barrier per half. Slot swizzle sp = kl ^ ((row>>1)&3). 2D XCD chunking.
template <int OUTF32>
__global__ __launch_bounds__(512, 2) void gemm256(const bf16* __restrict__ A,
                                                  const bf16* __restrict__ Bt,
                                                  void* __restrict__ Cp,
                                                  const int N, const int K,
                                                  const int ncc_l, const int cbx_l) {
  __shared__ __attribute__((aligned(16))) bf16 lds[5][2][8192];
  const int t = threadIdx.x, w = t >> 6, l = t & 63;
  const int la = l & 15, lq = l >> 4;
  const int xcd = blockIdx.x & 7, wi = blockIdx.x >> 3;
  const int cr = xcd >> ncc_l, cc = xcd & ((1 << ncc_l) - 1);
  const int by = (cr << 3) + (wi >> cbx_l);
  const int bx = (cc << cbx_l) + (wi & ((1 << cbx_l) - 1));
  const int m0 = by * 256, n0 = bx * 256;
  const int wr = w >> 2, wc = w & 3;
  const int c0 = w * 64 + l;
  const int sr0 = c0 >> 2, soff = (((c0 & 3) ^ ((c0 >> 3) & 3)) << 3);
  const bf16* pA0 = A + (size_t)(m0 + sr0) * K + soff;
  const bf16* pA1 = pA0 + (size_t)128 * K;
  const bf16* pB0 = Bt + (size_t)(n0 + sr0) * K + soff;
  const bf16* pB1 = pB0 + (size_t)128 * K;
  const int rsl = (lq ^ ((la >> 1) & 3)) << 3;

  f32x4 acc[8][4] = {};

#define STAGE_A(b_, H_)                                                       \
  do {                                                                        \
    gload_lds16(pA0 + (H_) * 32, &lds[b_][0][w * 512]);                       \
    gload_lds16(pA1 + (H_) * 32, &lds[b_][0][4096 + w * 512]);                \
  } while (0)
#define STAGE_B(b_, H_)                                                       \
  do {                                                                        \
    gload_lds16(pB0 + (H_) * 32, &lds[b_][1][w * 512]);                       \
    gload_lds16(pB1 + (H_) * 32, &lds[b_][1][4096 + w * 512]);                \
  } while (0)

#define LOAD_BFR(b_)                                                          \
  _Pragma("unroll") for (int n_ = 0; n_ < 4; ++n_)                            \
      bfr[n_] = *(const bf16x8*)&lds[b_][1][(wc * 64 + n_ * 16 + la) * 32 + rsl];

#define PHASE(b_, mg)                                                         \
  {                                                                           \
    bf16x8 a_[4];                                                             \
    _Pragma("unroll") for (int m_ = 0; m_ < 4; ++m_)                          \
        a_[m_] = *(const bf16x8*)&lds[b_][0][(wr * 128 + (mg)*64 + m_ * 16 + la) * 32 + rsl]; \
    __builtin_amdgcn_s_setprio(1);                                            \
    _Pragma("unroll") for (int m_ = 0; m_ < 4; ++m_)                          \
      _Pragma("unroll") for (int n_ = 0; n_ < 4; ++n_)                        \
          acc[(mg)*4 + m_][n_] = __builtin_amdgcn_mfma_f32_16x16x32_bf16(     \
              a_[m_], bfr[n_], acc[(mg)*4 + m_][n_], 0, 0, 0);                \
    __builtin_amdgcn_s_setprio(0);                                            \
  }

  // prologue: stage halves 0..3 into bufs 0..3 (16 loads in flight)
  STAGE_A(0, 0); STAGE_B(0, 0);
  STAGE_A(1, 1); STAGE_B(1, 1);
  STAGE_A(2, 2); STAGE_B(2, 2);
  STAGE_A(3, 3); STAGE_B(3, 3);

  const int NH = K >> 5;  // 32-wide kh-halves (NH >= 5 for K >= 160)
  int b = 0, nb = 4;
  for (int H = 0; H < NH; ++H) {
    bf16x8 bfr[4];
    if (H <= NH - 4)      asm volatile("s_waitcnt vmcnt(12)" ::: "memory");
    else if (H == NH - 3) asm volatile("s_waitcnt vmcnt(8)" ::: "memory");
    else if (H == NH - 2) asm volatile("s_waitcnt vmcnt(4)" ::: "memory");
    else                  asm volatile("s_waitcnt vmcnt(0)" ::: "memory");
    __builtin_amdgcn_s_barrier();
    __builtin_amdgcn_sched_barrier(0);
    if (H <= NH - 5) STAGE_A(nb, H + 4);
    LOAD_BFR(b)
    PHASE(b, 0)
    if (H <= NH - 5) STAGE_B(nb, H + 4);
    PHASE(b, 1)
    b = (b == 4) ? 0 : b + 1;
    nb = (nb == 4) ? 0 : nb + 1;
  }
#undef PHASE
#undef LOAD_BFR
#undef STAGE_B
#undef STAGE_A

  const int crow = m0 + wr * 128, ccol = n0 + wc * 64;
  if (OUTF32) {
    float* C = (float*)Cp;
#pragma unroll
    for (int mi = 0; mi < 8; ++mi)
#pragma unroll
      for (int ni = 0; ni < 4; ++ni)
#pragma unroll
        for (int i = 0; i < 4; ++i)
          C[(size_t)(crow + mi * 16 + lq * 4 + i) * N + ccol + ni * 16 + la] = acc[mi][ni][i];
  } else {
    bf16* C = (bf16*)Cp;
#pragma unroll
    for (int mi = 0; mi < 8; ++mi)
#pragma unroll
      for (int ni = 0; ni < 4; ++ni)
#pragma unroll
        for (int i = 0; i < 4; ++i)
          C[(size_t)(crow + mi * 16 + lq * 4 + i) * N + ccol + ni * 16 + la] = (bf16)acc[mi][ni][i];
  }
}

// ------- RoPE on q (in fused qkv, row stride 8192; folds 1/sqrt(HD)) -------
__global__ __launch_bounds__(256) void rope_q(bf16* __restrict__ qkv, const int* __restrict__ pos) {
  const int w = threadIdx.x >> 6, l = threadIdx.x & 63;
  const int idx = blockIdx.x * 4 + w;
  const int bt = idx >> 4, h = idx & 15;  // HQ=16
  bf16* p = qkv + (size_t)bt * 8192 + h * 256 + l * 4;
  bf16x4 xv = *(const bf16x4*)p;
  float x[4], y[4];
#pragma unroll
  for (int j = 0; j < 4; ++j) x[j] = (float)xv[j];
#pragma unroll
  for (int j = 0; j < 4; ++j) y[j] = __shfl_xor(x[j], 32, 64);
  const float posf = (float)pos[bt];
  bf16x4 ov;
#pragma unroll
  for (int j = 0; j < 4; ++j) {
    const int pr = (l & 31) * 4 + j;  // pair index 0..127
    float sv, cv;
    sincosf(posf * exp2f((float)pr * (-13.287712379549449f / 128.0f)), &sv, &cv);
    float o = x[j] * cv + ((l < 32) ? -y[j] : y[j]) * sv;
    ov[j] = (bf16)(o * 0.0625f);  // 1/sqrt(256), exact pow2
  }
  *(bf16x4*)p = ov;
}

// ------- RMSNorm + RoPE on k (fused qkv +4096, row stride 8192) -------
__global__ __launch_bounds__(256) void norm_rope_k(bf16* __restrict__ kbase,
                                                   const float* __restrict__ scale,
                                                   const int* __restrict__ pos) {
  const int w = threadIdx.x >> 6, l = threadIdx.x & 63;
  const int idx = blockIdx.x * 4 + w;
  const int bt = idx >> 3, h = idx & 7;  // HKV=8
  bf16* p = kbase + (size_t)bt * 8192 + h * 256 + l * 4;
  bf16x4 xv = *(const bf16x4*)p;
  float x[4];
#pragma unroll
  for (int j = 0; j < 4; ++j) x[j] = (float)xv[j];
  float ss = x[0] * x[0] + x[1] * x[1] + x[2] * x[2] + x[3] * x[3];
#pragma unroll
  for (int m = 1; m < 64; m <<= 1) ss += __shfl_xor(ss, m, 64);
  const float r = rsqrtf(ss * (1.0f / 256.0f) + 1e-6f);
#pragma unroll
  for (int j = 0; j < 4; ++j) x[j] = x[j] * r * (1.0f + scale[l * 4 + j]);
  float y[4];
#pragma unroll
  for (int j = 0; j < 4; ++j) y[j] = __shfl_xor(x[j], 32, 64);
  const float posf = (float)pos[bt];
  bf16x4 ov;
#pragma unroll
  for (int j = 0; j < 4; ++j) {
    const int pr = (l & 31) * 4 + j;
    float sv, cv;
    sincosf(posf * exp2f((float)pr * (-13.287712379549449f / 128.0f)), &sv, &cv);
    float o = x[j] * cv + ((l < 32) ? -y[j] : y[j]) * sv;
    ov[j] = (bf16)o;
  }
  *(bf16x4*)p = ov;
}

// ------- RMSNorm on v (fused qkv +6144, row stride 8192) -------
__global__ __launch_bounds__(256) void norm_v(bf16* __restrict__ vbase,
                                              const float* __restrict__ scale) {
  const int w = threadIdx.x >> 6, l = threadIdx.x & 63;
  const int idx = blockIdx.x * 4 + w;
  const int bt = idx >> 3, h = idx & 7;
  bf16* p = vbase + (size_t)bt * 8192 + h * 256 + l * 4;
  bf16x4 xv = *(const bf16x4*)p;
  float x[4];
#pragma unroll
  for (int j = 0; j < 4; ++j) x[j] = (float)xv[j];
  float ss = x[0] * x[0] + x[1] * x[1] + x[2] * x[2] + x[3] * x[3];
#pragma unroll
  for (int m = 1; m < 64; m <<= 1) ss += __shfl_xor(ss, m, 64);
  const float r = rsqrtf(ss * (1.0f / 256.0f) + 1e-6f);
  bf16x4 ov;
#pragma unroll
  for (int j = 0; j < 4; ++j) ov[j] = (bf16)(x[j] * r * (1.0f + scale[l * 4 + j]));
  *(bf16x4*)p = ov;
}

// -------- v (in fused qkv) -> vt [b,hkv,d,t] (tiled transpose, bf16) --------
// Vectorized: bf16x4 global reads AND writes via padded LDS tile.
__global__ __launch_bounds__(256) void vtrans(const bf16* __restrict__ vbase,
                                              bf16* __restrict__ vt) {
  __shared__ bf16 tile[64][68];  // [d][t]
  const int tt = blockIdx.x, dd = blockIdx.y, bh = blockIdx.z;
  const int b = bh >> 3, h = bh & 7;
  const int u4 = threadIdx.x & 15, r0 = threadIdx.x >> 4;
#pragma unroll
  for (int i = 0; i < 4; ++i) {
    int tr = r0 + i * 16;
    bf16x4 v = *(const bf16x4*)&vbase[(size_t)(b * 2048 + tt * 64 + tr) * 8192 + h * 256 + dd * 64 + u4 * 4];
#pragma unroll
    for (int j = 0; j < 4; ++j) tile[u4 * 4 + j][tr] = v[j];
  }
  __syncthreads();
#pragma unroll
  for (int i = 0; i < 4; ++i) {
    int dr = r0 + i * 16;
    bf16x4 o;
#pragma unroll
    for (int j = 0; j < 4; ++j) o[j] = tile[dr][u4 * 4 + j];
    *(bf16x4*)&vt[((size_t)(b * 8 + h) * 256 + dd * 64 + dr) * 2048 + tt * 64 + u4 * 4] = o;
  }
}

// ---------------- flash attention (causal, GQA group=2) ----------------
// block = (h, qbp, b): processes qb pair {15-qbp, qbp} (34 K/V tiles each,
// 256 blocks = 1/CU). K read from fused qkv (row stride 8192).
// T13 defer-max: skip O-rescale + m-update when tile max grows < 8.
__global__ __launch_bounds__(512, 2) void flash_attn(const bf16* __restrict__ qkv,
                                                     const bf16* __restrict__ vt,
                                                     bf16* __restrict__ o) {
  __shared__ __attribute__((aligned(16))) bf16 Ks[2 * 16384];
  __shared__ __attribute__((aligned(16))) bf16 Vs[2 * 16384];
  __shared__ __attribute__((aligned(16))) bf16 Ps[8 * 1152];  // per-wave [16][72]
  const int t = threadIdx.x, w = t >> 6, l = t & 63;
  const int la = l & 15, lq = l >> 4;
  const int h = blockIdx.x, qbp = blockIdx.y, b = blockIdx.z;
  const int hkv = h >> 1;

  const bf16* kbase = qkv + (size_t)(b * 2048) * 8192 + 4096 + hkv * 256;
  const bf16* vbase = vt + ((size_t)(b * 8 + hkv)) * 256 * 2048;

  const bf16* ksrc[4];
  const bf16* vsrc[4];
#pragma unroll
  for (int i = 0; i < 4; ++i) {
    int c = i * 512 + t;
    int krr = c >> 5, ksl = (c & 31) ^ (krr & 7);
    int vrr = c >> 3, vsl = (c & 7) ^ (vrr & 7);
    ksrc[i] = kbase + (size_t)krr * 8192 + ksl * 8;
    vsrc[i] = vbase + (size_t)vrr * 2048 + vsl * 8;
  }

#define STAGE(bb, tt0)                                                        \
  do {                                                                        \
    _Pragma("unroll") for (int i_ = 0; i_ < 4; ++i_)                          \
        gload_lds16(ksrc[i_] + (size_t)(tt0) * 8192,                          \
                    Ks + (bb) * 16384 + i_ * 4096 + w * 512);                 \
    _Pragma("unroll") for (int i_ = 0; i_ < 4; ++i_)                          \
        gload_lds16(vsrc[i_] + (tt0), Vs + (bb) * 16384 + i_ * 4096 + w * 512); \
  } while (0)

  for (int part = 0; part < 2; ++part) {
    const int qb = part ? qbp : (15 - qbp);
    const int q0 = qb * 128;
    const int rbase = q0 + w * 16;

    bf16x8 qf[8];
    {
      const bf16* qrow = qkv + (size_t)(b * 2048 + rbase + la) * 8192 + h * 256 + lq * 8;
#pragma unroll
      for (int kg = 0; kg < 8; ++kg) qf[kg] = *(const bf16x8*)(qrow + kg * 32);
    }
    f32x4 acc[16] = {};
    float mrow[4] = {-1e30f, -1e30f, -1e30f, -1e30f};
    float lrow[4] = {0.f, 0.f, 0.f, 0.f};
    const int nT = 2 * qb + 2;

    STAGE(0, 0);
    int cur = 0;
    for (int tti = 0; tti < nT; ++tti) {
      const int t0 = tti * 64;
      if (tti + 1 < nT) {
        STAGE(cur ^ 1, t0 + 64);
        asm volatile("s_waitcnt vmcnt(8)" ::: "memory");  // cur landed, next flies
      } else {
        asm volatile("s_waitcnt vmcnt(0)" ::: "memory");
      }
      __builtin_amdgcn_s_barrier();
      __builtin_amdgcn_sched_barrier(0);
      if (t0 <= rbase + 15) {
        const bf16* Kc = Ks + cur * 16384;
        const bf16* Vc = Vs + cur * 16384;
        f32x4 s[4] = {};
        __builtin_amdgcn_s_setprio(1);
#pragma unroll
        for (int n = 0; n < 4; ++n) {
          int rT = n * 16 + la;
#pragma unroll
          for (int kg = 0; kg < 8; ++kg) {
            int sl = (kg * 4 + lq) ^ (rT & 7);
            bf16x8 kbv = *(const bf16x8*)(Kc + rT * 256 + sl * 8);
            s[n] = __builtin_amdgcn_mfma_f32_16x16x32_bf16(qf[kg], kbv, s[n], 0, 0, 0);
          }
        }
        __builtin_amdgcn_s_setprio(0);
        // pass 1: causal mask + per-row tile max
        float mxr[4];
        float need = -1.f;
#pragma unroll
        for (int i = 0; i < 4; ++i) {
          const int row = rbase + lq * 4 + i;
          float mx = -1e30f;
#pragma unroll
          for (int n = 0; n < 4; ++n) {
            float v = s[n][i];
            v = (t0 + n * 16 + la > row) ? -1e30f : v;
            s[n][i] = v;
            mx = fmaxf(mx, v);
          }
          mx = fmaxf(mx, __shfl_xor(mx, 1, 64));
          mx = fmaxf(mx, __shfl_xor(mx, 2, 64));
          mx = fmaxf(mx, __shfl_xor(mx, 4, 64));
          mx = fmaxf(mx, __shfl_xor(mx, 8, 64));
          mxr[i] = mx;
          need = fmaxf(need, mx - mrow[i]);
        }
        const bool resc = __any(need > 8.0f);
        float scalef[4];
        if (resc) {
#pragma unroll
          for (int i = 0; i < 4; ++i) {
            const float mnew = fmaxf(mrow[i], mxr[i]);
            scalef[i] = __expf(mrow[i] - mnew);
            mrow[i] = mnew;
          }
        }
        // pass 2: exp + row sum
#pragma unroll
        for (int i = 0; i < 4; ++i) {
          float ps = 0.f;
#pragma unroll
          for (int n = 0; n < 4; ++n) {
            float v = s[n][i];
            float pp = (v <= -1e29f) ? 0.f : __expf(v - mrow[i]);
            s[n][i] = pp;
            ps += pp;
          }
          ps += __shfl_xor(ps, 1, 64);
          ps += __shfl_xor(ps, 2, 64);
          ps += __shfl_xor(ps, 4, 64);
          ps += __shfl_xor(ps, 8, 64);
          lrow[i] = resc ? (lrow[i] * scalef[i] + ps) : (lrow[i] + ps);
        }
        if (resc) {
#pragma unroll
          for (int n = 0; n < 16; ++n) {
            acc[n][0] *= scalef[0]; acc[n][1] *= scalef[1];
            acc[n][2] *= scalef[2]; acc[n][3] *= scalef[3];
          }
        }
        bf16* pw = Ps + w * 1152;
#pragma unroll
        for (int n = 0; n < 4; ++n)
#pragma unroll
          for (int i = 0; i < 4; ++i)
            pw[(lq * 4 + i) * 72 + n * 16 + la] = (bf16)s[n][i];
        __builtin_amdgcn_s_setprio(1);
#pragma unroll
        for (int kc = 0; kc < 2; ++kc) {
          bf16x8 pa = *(const bf16x8*)(pw + la * 72 + kc * 32 + lq * 8);
#pragma unroll
          for (int n = 0; n < 16; ++n) {
            int rd = n * 16 + la;
            int sl = (kc * 4 + lq) ^ (rd & 7);
            bf16x8 vbv = *(const bf16x8*)(Vc + rd * 64 + sl * 8);
            acc[n] = __builtin_amdgcn_mfma_f32_16x16x32_bf16(pa, vbv, acc[n], 0, 0, 0);
          }
        }
        __builtin_amdgcn_s_setprio(0);
      }
      __builtin_amdgcn_s_barrier();
      __builtin_amdgcn_sched_barrier(0);
      cur ^= 1;
    }
#pragma unroll
    for (int i = 0; i < 4; ++i) {
      const int row = rbase + lq * 4 + i;
      const float inv = 1.0f / lrow[i];
      bf16* orow = o + ((size_t)(b * 2048 + row)) * 4096 + h * 256;
#pragma unroll
      for (int n = 0; n < 16; ++n) orow[n * 16 + la] = (bf16)(acc[n][i] * inv);
    }
  }
#undef STAGE
}

// ---------------- diagnostic fill if ws too small ----------------
__global__ void fill_err(float* o, int n) {
  int i = blockIdx.x * 256 + threadIdx.x;
  if (i < n) o[i] = 1e9f;
}

extern "C" void kernel_launch(void* const* d_in, const int* in_sizes, int n_in,
                              void* d_out, int out_size, void* d_ws, size_t ws_size,
                              hipStream_t stream) {
  const float* x = (const float*)d_in[0];
  const float* Wq = (const float*)d_in[1];
  const float* Wk = (const float*)d_in[2];
  const float* Wv = (const float*)d_in[3];
  const float* Wo = (const float*)d_in[4];
  const float* kscale = (const float*)d_in[5];
  const float* vscale = (const float*)d_in[6];
  const int* pos = (const int*)d_in[8];
  float* out = (float*)d_out;

  const size_t WS_NEED = 251658240ull;  // 240 MB
  if (ws_size < WS_NEED) {
    fill_err<<<65536, 256, 0, stream>>>(out, out_size);
    return;
  }
  char* ws = (char*)d_ws;
  bf16* x16   = (bf16*)(ws);                  // [4096][4096]   32 MB
  bf16* wqkvt = (bf16*)(ws + 33554432);       // [8192][4096]   64 MB (Q|K|V rows)
  bf16* wot   = (bf16*)(ws + 100663296);      // [4096][4096]   32 MB
  bf16* qkv   = (bf16*)(ws + 134217728);      // [4096][8192]   64 MB (Q|K|V cols)
  bf16* vtb   = (bf16*)(ws + 201326592);      // [2][8][256][2048] 16 MB
  bf16* ao    = (bf16*)(ws + 218103808);      // [4096][4096]   32 MB

  // prep: bf16 conversions + weight transposes (concatenated along N)
  cvt_bf16<<<16384, 256, 0, stream>>>(x, x16, 4194304);
  tconv<<<dim3(64, 64), 256, 0, stream>>>(Wq, wqkvt, 4096, 4096);
  tconv<<<dim3(32, 64), 256, 0, stream>>>(Wk, wqkvt + (size_t)4096 * 4096, 4096, 2048);
  tconv<<<dim3(32, 64), 256, 0, stream>>>(Wv, wqkvt + (size_t)6144 * 4096, 4096, 2048);
  tconv<<<dim3(64, 64), 256, 0, stream>>>(Wo, wot, 4096, 4096);

  // fused QKV projection: [4096][8192] = x16 @ wqkvt^T
  // grid 512: 16x32 btiles; per-XCD chunk = 8 by x 8 bx (ncc_l=2, cbx_l=3)
  gemm256<0><<<512, 512, 0, stream>>>(x16, wqkvt, qkv, 8192, 4096, 2, 3);

  // norms + rope on fused layout (q pre-scaled by 1/sqrt(HD))
  rope_q<<<16384, 256, 0, stream>>>(qkv, pos);
  norm_rope_k<<<8192, 256, 0, stream>>>(qkv + 4096, kscale, pos);
  norm_v<<<8192, 256, 0, stream>>>(qkv + 6144, vscale);
  vtrans<<<dim3(32, 4, 16), 256, 0, stream>>>(qkv + 6144, vtb);

  // attention: paired-qb load-balanced grid (256 blocks = 1/CU)
  flash_attn<<<dim3(16, 8, 2), 512, 0, stream>>>(qkv, vtb, ao);

  // output projection (fp32 out): grid 256: 16x16 btiles; chunk = 8 by x 4 bx
  gemm256<1><<<256, 512, 0, stream>>>(ao, wot, out, 4096, 4096, 2, 2);
}

// Round 16
// 623.145 us; speedup vs baseline: 1.0034x; 1.0034x over previous
//
#include <hip/hip_runtime.h>
#include <stdint.h>

typedef __bf16 bf16;
typedef __bf16 bf16x4 __attribute__((ext_vector_type(4)));
typedef __bf16 bf16x8 __attribute__((ext_vector_type(8)));
typedef float f32x4 __attribute__((ext_vector_type(4)));

#define GAS __attribute__((address_space(1)))
#define LAS __attribute__((address_space(3)))

__device__ __forceinline__ void gload_lds16(const void* g, void* l) {
  __builtin_amdgcn_global_load_lds((GAS const void*)g, (LAS void*)l, 16, 0, 0);
}

// ---------------- fp32 -> bf16 convert (x) ----------------
__global__ __launch_bounds__(256) void cvt_bf16(const float* __restrict__ in,
                                                bf16* __restrict__ out, int n4) {
  int i = blockIdx.x * 256 + threadIdx.x;
  if (i >= n4) return;
  float4 v = ((const float4*)in)[i];
  bf16x4 o;
  o[0] = (bf16)v.x; o[1] = (bf16)v.y; o[2] = (bf16)v.z; o[3] = (bf16)v.w;
  ((bf16x4*)out)[i] = o;
}

// ------------- W[K][N] f32 -> Wt[N][K] bf16 (transpose+convert) -------------
// Vectorized: float2 reads (8B/lane), bf16x4 writes (8B/lane, coalesced).
__global__ __launch_bounds__(256) void tconv(const float* __restrict__ W,
                                             bf16* __restrict__ Wt, int K, int N) {
  __shared__ bf16 tile[64][68];
  const int n0 = blockIdx.x * 64, k0 = blockIdx.y * 64;
  const int u2 = threadIdx.x & 31, kr0 = threadIdx.x >> 5;  // 32 n-pairs x 8 k-rows
#pragma unroll
  for (int i = 0; i < 8; ++i) {
    int kr = kr0 + i * 8;
    float2 v = *(const float2*)&W[(size_t)(k0 + kr) * N + n0 + u2 * 2];
    tile[kr][u2 * 2] = (bf16)v.x;
    tile[kr][u2 * 2 + 1] = (bf16)v.y;
  }
  __syncthreads();
  const int u4 = threadIdx.x & 15, nr0 = threadIdx.x >> 4;  // 16 k-quads x 16 n-rows
#pragma unroll
  for (int i = 0; i < 4; ++i) {
    int nr = nr0 + i * 16;
    bf16x4 o;
#pragma unroll
    for (int j = 0; j < 4; ++j) o[j] = tile[u4 * 4 + j][nr];
    *(bf16x4*)&Wt[(size_t)(n0 + nr) * K + k0 + u4 * 4] = o;
  }
}

// ============ 256x256 bf16 GEMM, depth-3 half-tile pipeline ============
// BK=64 processed as 2 kh-halves; LDS = 4 half-buffers[A 8192 | B 8192] =128KB.
// Half H uses buf H&3; its loads were issued 3 halves (~930cy) earlier ->
// covers HBM latency (~900cy). Steady state: 12 loads in flight, vmcnt(8)
// per boundary (retire current half's 4), 1 barrier per half (2/K-tile, same
// as r5). Slot swizzle sp = kl ^ ((row>>1)&3). 2D XCD chunking.
// Depth ladder measured: depth1.5=50%, depth3=52.8%, depth4=49.1% MfmaUtil ->
// depth-3 with compile-time buffer indices is the optimum of this family.
template <int OUTF32>
__global__ __launch_bounds__(512, 2) void gemm256(const bf16* __restrict__ A,
                                                  const bf16* __restrict__ Bt,
                                                  void* __restrict__ Cp,
                                                  const int N, const int K,
                                                  const int ncc_l, const int cbx_l) {
  __shared__ __attribute__((aligned(16))) bf16 lds[4][2][8192];
  const int t = threadIdx.x, w = t >> 6, l = t & 63;
  const int la = l & 15, lq = l >> 4;
  const int xcd = blockIdx.x & 7, wi = blockIdx.x >> 3;
  const int cr = xcd >> ncc_l, cc = xcd & ((1 << ncc_l) - 1);
  const int by = (cr << 3) + (wi >> cbx_l);
  const int bx = (cc << cbx_l) + (wi & ((1 << cbx_l) - 1));
  const int m0 = by * 256, n0 = bx * 256;
  const int wr = w >> 2, wc = w & 3;
  const int c0 = w * 64 + l;
  const int sr0 = c0 >> 2, soff = (((c0 & 3) ^ ((c0 >> 3) & 3)) << 3);
  const bf16* pA0 = A + (size_t)(m0 + sr0) * K + soff;
  const bf16* pA1 = pA0 + (size_t)128 * K;
  const bf16* pB0 = Bt + (size_t)(n0 + sr0) * K + soff;
  const bf16* pB1 = pB0 + (size_t)128 * K;
  const int rsl = (lq ^ ((la >> 1) & 3)) << 3;

  f32x4 acc[8][4] = {};

#define STAGE_A(b_, H_)                                                       \
  do {                                                                        \
    gload_lds16(pA0 + (H_) * 32, &lds[b_][0][w * 512]);                       \
    gload_lds16(pA1 + (H_) * 32, &lds[b_][0][4096 + w * 512]);                \
  } while (0)
#define STAGE_B(b_, H_)                                                       \
  do {                                                                        \
    gload_lds16(pB0 + (H_) * 32, &lds[b_][1][w * 512]);                       \
    gload_lds16(pB1 + (H_) * 32, &lds[b_][1][4096 + w * 512]);                \
  } while (0)

#define LOAD_BFR(b_)                                                          \
  _Pragma("unroll") for (int n_ = 0; n_ < 4; ++n_)                            \
      bfr[n_] = *(const bf16x8*)&lds[b_][1][(wc * 64 + n_ * 16 + la) * 32 + rsl];

#define PHASE(b_, mg)                                                         \
  {                                                                           \
    bf16x8 a_[4];                                                             \
    _Pragma("unroll") for (int m_ = 0; m_ < 4; ++m_)                          \
        a_[m_] = *(const bf16x8*)&lds[b_][0][(wr * 128 + (mg)*64 + m_ * 16 + la) * 32 + rsl]; \
    __builtin_amdgcn_s_setprio(1);                                            \
    _Pragma("unroll") for (int m_ = 0; m_ < 4; ++m_)                          \
      _Pragma("unroll") for (int n_ = 0; n_ < 4; ++n_)                        \
          acc[(mg)*4 + m_][n_] = __builtin_amdgcn_mfma_f32_16x16x32_bf16(     \
              a_[m_], bfr[n_], acc[(mg)*4 + m_][n_], 0, 0, 0);                \
    __builtin_amdgcn_s_setprio(0);                                            \
  }

  // prologue: stage halves 0..2 into bufs 0..2 (12 loads in flight)
  STAGE_A(0, 0); STAGE_B(0, 0);
  STAGE_A(1, 1); STAGE_B(1, 1);
  STAGE_A(2, 2); STAGE_B(2, 2);

  const int NH = K >> 5;  // 32-wide kh-halves
  for (int H = 0; H <= NH - 4; ++H) {
    const int b = H & 3, nb = (H + 3) & 3;
    bf16x8 bfr[4];
    asm volatile("s_waitcnt vmcnt(8)" ::: "memory");  // half H landed; H+1,H+2 fly
    __builtin_amdgcn_s_barrier();
    __builtin_amdgcn_sched_barrier(0);
    STAGE_A(nb, H + 3);
    LOAD_BFR(b)
    PHASE(b, 0)
    STAGE_B(nb, H + 3);
    PHASE(b, 1)
  }
  {  // H = NH-3: no more staging; outstanding 12 -> retire this half
    const int b = (NH - 3) & 3;
    bf16x8 bfr[4];
    asm volatile("s_waitcnt vmcnt(8)" ::: "memory");
    __builtin_amdgcn_s_barrier();
    __builtin_amdgcn_sched_barrier(0);
    LOAD_BFR(b)
    PHASE(b, 0)
    PHASE(b, 1)
  }
  {  // H = NH-2
    const int b = (NH - 2) & 3;
    bf16x8 bfr[4];
    asm volatile("s_waitcnt vmcnt(4)" ::: "memory");
    __builtin_amdgcn_s_barrier();
    __builtin_amdgcn_sched_barrier(0);
    LOAD_BFR(b)
    PHASE(b, 0)
    PHASE(b, 1)
  }
  {  // H = NH-1
    const int b = (NH - 1) & 3;
    bf16x8 bfr[4];
    asm volatile("s_waitcnt vmcnt(0)" ::: "memory");
    __builtin_amdgcn_s_barrier();
    __builtin_amdgcn_sched_barrier(0);
    LOAD_BFR(b)
    PHASE(b, 0)
    PHASE(b, 1)
  }
#undef PHASE
#undef LOAD_BFR
#undef STAGE_B
#undef STAGE_A

  const int crow = m0 + wr * 128, ccol = n0 + wc * 64;
  if (OUTF32) {
    float* C = (float*)Cp;
#pragma unroll
    for (int mi = 0; mi < 8; ++mi)
#pragma unroll
      for (int ni = 0; ni < 4; ++ni)
#pragma unroll
        for (int i = 0; i < 4; ++i)
          C[(size_t)(crow + mi * 16 + lq * 4 + i) * N + ccol + ni * 16 + la] = acc[mi][ni][i];
  } else {
    bf16* C = (bf16*)Cp;
#pragma unroll
    for (int mi = 0; mi < 8; ++mi)
#pragma unroll
      for (int ni = 0; ni < 4; ++ni)
#pragma unroll
        for (int i = 0; i < 4; ++i)
          C[(size_t)(crow + mi * 16 + lq * 4 + i) * N + ccol + ni * 16 + la] = (bf16)acc[mi][ni][i];
  }
}

// ------- RoPE on q (in fused qkv, row stride 8192; folds 1/sqrt(HD)) -------
__global__ __launch_bounds__(256) void rope_q(bf16* __restrict__ qkv, const int* __restrict__ pos) {
  const int w = threadIdx.x >> 6, l = threadIdx.x & 63;
  const int idx = blockIdx.x * 4 + w;
  const int bt = idx >> 4, h = idx & 15;  // HQ=16
  bf16* p = qkv + (size_t)bt * 8192 + h * 256 + l * 4;
  bf16x4 xv = *(const bf16x4*)p;
  float x[4], y[4];
#pragma unroll
  for (int j = 0; j < 4; ++j) x[j] = (float)xv[j];
#pragma unroll
  for (int j = 0; j < 4; ++j) y[j] = __shfl_xor(x[j], 32, 64);
  const float posf = (float)pos[bt];
  bf16x4 ov;
#pragma unroll
  for (int j = 0; j < 4; ++j) {
    const int pr = (l & 31) * 4 + j;  // pair index 0..127
    float sv, cv;
    sincosf(posf * exp2f((float)pr * (-13.287712379549449f / 128.0f)), &sv, &cv);
    float o = x[j] * cv + ((l < 32) ? -y[j] : y[j]) * sv;
    ov[j] = (bf16)(o * 0.0625f);  // 1/sqrt(256), exact pow2
  }
  *(bf16x4*)p = ov;
}

// ------- RMSNorm + RoPE on k (fused qkv +4096, row stride 8192) -------
__global__ __launch_bounds__(256) void norm_rope_k(bf16* __restrict__ kbase,
                                                   const float* __restrict__ scale,
                                                   const int* __restrict__ pos) {
  const int w = threadIdx.x >> 6, l = threadIdx.x & 63;
  const int idx = blockIdx.x * 4 + w;
  const int bt = idx >> 3, h = idx & 7;  // HKV=8
  bf16* p = kbase + (size_t)bt * 8192 + h * 256 + l * 4;
  bf16x4 xv = *(const bf16x4*)p;
  float x[4];
#pragma unroll
  for (int j = 0; j < 4; ++j) x[j] = (float)xv[j];
  float ss = x[0] * x[0] + x[1] * x[1] + x[2] * x[2] + x[3] * x[3];
#pragma unroll
  for (int m = 1; m < 64; m <<= 1) ss += __shfl_xor(ss, m, 64);
  const float r = rsqrtf(ss * (1.0f / 256.0f) + 1e-6f);
#pragma unroll
  for (int j = 0; j < 4; ++j) x[j] = x[j] * r * (1.0f + scale[l * 4 + j]);
  float y[4];
#pragma unroll
  for (int j = 0; j < 4; ++j) y[j] = __shfl_xor(x[j], 32, 64);
  const float posf = (float)pos[bt];
  bf16x4 ov;
#pragma unroll
  for (int j = 0; j < 4; ++j) {
    const int pr = (l & 31) * 4 + j;
    float sv, cv;
    sincosf(posf * exp2f((float)pr * (-13.287712379549449f / 128.0f)), &sv, &cv);
    float o = x[j] * cv + ((l < 32) ? -y[j] : y[j]) * sv;
    ov[j] = (bf16)o;
  }
  *(bf16x4*)p = ov;
}

// ------- RMSNorm on v (fused qkv +6144, row stride 8192) -------
__global__ __launch_bounds__(256) void norm_v(bf16* __restrict__ vbase,
                                              const float* __restrict__ scale) {
  const int w = threadIdx.x >> 6, l = threadIdx.x & 63;
  const int idx = blockIdx.x * 4 + w;
  const int bt = idx >> 3, h = idx & 7;
  bf16* p = vbase + (size_t)bt * 8192 + h * 256 + l * 4;
  bf16x4 xv = *(const bf16x4*)p;
  float x[4];
#pragma unroll
  for (int j = 0; j < 4; ++j) x[j] = (float)xv[j];
  float ss = x[0] * x[0] + x[1] * x[1] + x[2] * x[2] + x[3] * x[3];
#pragma unroll
  for (int m = 1; m < 64; m <<= 1) ss += __shfl_xor(ss, m, 64);
  const float r = rsqrtf(ss * (1.0f / 256.0f) + 1e-6f);
  bf16x4 ov;
#pragma unroll
  for (int j = 0; j < 4; ++j) ov[j] = (bf16)(x[j] * r * (1.0f + scale[l * 4 + j]));
  *(bf16x4*)p = ov;
}

// -------- v (in fused qkv) -> vt [b,hkv,d,t] (tiled transpose, bf16) --------
// Vectorized: bf16x4 global reads AND writes via padded LDS tile.
__global__ __launch_bounds__(256) void vtrans(const bf16* __restrict__ vbase,
                                              bf16* __restrict__ vt) {
  __shared__ bf16 tile[64][68];  // [d][t]
  const int tt = blockIdx.x, dd = blockIdx.y, bh = blockIdx.z;
  const int b = bh >> 3, h = bh & 7;
  const int u4 = threadIdx.x & 15, r0 = threadIdx.x >> 4;
#pragma unroll
  for (int i = 0; i < 4; ++i) {
    int tr = r0 + i * 16;
    bf16x4 v = *(const bf16x4*)&vbase[(size_t)(b * 2048 + tt * 64 + tr) * 8192 + h * 256 + dd * 64 + u4 * 4];
#pragma unroll
    for (int j = 0; j < 4; ++j) tile[u4 * 4 + j][tr] = v[j];
  }
  __syncthreads();
#pragma unroll
  for (int i = 0; i < 4; ++i) {
    int dr = r0 + i * 16;
    bf16x4 o;
#pragma unroll
    for (int j = 0; j < 4; ++j) o[j] = tile[dr][u4 * 4 + j];
    *(bf16x4*)&vt[((size_t)(b * 8 + h) * 256 + dd * 64 + dr) * 2048 + tt * 64 + u4 * 4] = o;
  }
}

// ---------------- flash attention (causal, GQA group=2) ----------------
// block = (h, qbp, b): processes qb pair {15-qbp, qbp} (34 K/V tiles each,
// 256 blocks = 1/CU). K read from fused qkv (row stride 8192).
// T13 defer-max: skip O-rescale + m-update when tile max grows < 8.
__global__ __launch_bounds__(512, 2) void flash_attn(const bf16* __restrict__ qkv,
                                                     const bf16* __restrict__ vt,
                                                     bf16* __restrict__ o) {
  __shared__ __attribute__((aligned(16))) bf16 Ks[2 * 16384];
  __shared__ __attribute__((aligned(16))) bf16 Vs[2 * 16384];
  __shared__ __attribute__((aligned(16))) bf16 Ps[8 * 1152];  // per-wave [16][72]
  const int t = threadIdx.x, w = t >> 6, l = t & 63;
  const int la = l & 15, lq = l >> 4;
  const int h = blockIdx.x, qbp = blockIdx.y, b = blockIdx.z;
  const int hkv = h >> 1;

  const bf16* kbase = qkv + (size_t)(b * 2048) * 8192 + 4096 + hkv * 256;
  const bf16* vbase = vt + ((size_t)(b * 8 + hkv)) * 256 * 2048;

  const bf16* ksrc[4];
  const bf16* vsrc[4];
#pragma unroll
  for (int i = 0; i < 4; ++i) {
    int c = i * 512 + t;
    int krr = c >> 5, ksl = (c & 31) ^ (krr & 7);
    int vrr = c >> 3, vsl = (c & 7) ^ (vrr & 7);
    ksrc[i] = kbase + (size_t)krr * 8192 + ksl * 8;
    vsrc[i] = vbase + (size_t)vrr * 2048 + vsl * 8;
  }

#define STAGE(bb, tt0)                                                        \
  do {                                                                        \
    _Pragma("unroll") for (int i_ = 0; i_ < 4; ++i_)                          \
        gload_lds16(ksrc[i_] + (size_t)(tt0) * 8192,                          \
                    Ks + (bb) * 16384 + i_ * 4096 + w * 512);                 \
    _Pragma("unroll") for (int i_ = 0; i_ < 4; ++i_)                          \
        gload_lds16(vsrc[i_] + (tt0), Vs + (bb) * 16384 + i_ * 4096 + w * 512); \
  } while (0)

  for (int part = 0; part < 2; ++part) {
    const int qb = part ? qbp : (15 - qbp);
    const int q0 = qb * 128;
    const int rbase = q0 + w * 16;

    bf16x8 qf[8];
    {
      const bf16* qrow = qkv + (size_t)(b * 2048 + rbase + la) * 8192 + h * 256 + lq * 8;
#pragma unroll
      for (int kg = 0; kg < 8; ++kg) qf[kg] = *(const bf16x8*)(qrow + kg * 32);
    }
    f32x4 acc[16] = {};
    float mrow[4] = {-1e30f, -1e30f, -1e30f, -1e30f};
    float lrow[4] = {0.f, 0.f, 0.f, 0.f};
    const int nT = 2 * qb + 2;

    STAGE(0, 0);
    int cur = 0;
    for (int tti = 0; tti < nT; ++tti) {
      const int t0 = tti * 64;
      if (tti + 1 < nT) {
        STAGE(cur ^ 1, t0 + 64);
        asm volatile("s_waitcnt vmcnt(8)" ::: "memory");  // cur landed, next flies
      } else {
        asm volatile("s_waitcnt vmcnt(0)" ::: "memory");
      }
      __builtin_amdgcn_s_barrier();
      __builtin_amdgcn_sched_barrier(0);
      if (t0 <= rbase + 15) {
        const bf16* Kc = Ks + cur * 16384;
        const bf16* Vc = Vs + cur * 16384;
        f32x4 s[4] = {};
        __builtin_amdgcn_s_setprio(1);
#pragma unroll
        for (int n = 0; n < 4; ++n) {
          int rT = n * 16 + la;
#pragma unroll
          for (int kg = 0; kg < 8; ++kg) {
            int sl = (kg * 4 + lq) ^ (rT & 7);
            bf16x8 kbv = *(const bf16x8*)(Kc + rT * 256 + sl * 8);
            s[n] = __builtin_amdgcn_mfma_f32_16x16x32_bf16(qf[kg], kbv, s[n], 0, 0, 0);
          }
        }
        __builtin_amdgcn_s_setprio(0);
        // pass 1: causal mask + per-row tile max
        float mxr[4];
        float need = -1.f;
#pragma unroll
        for (int i = 0; i < 4; ++i) {
          const int row = rbase + lq * 4 + i;
          float mx = -1e30f;
#pragma unroll
          for (int n = 0; n < 4; ++n) {
            float v = s[n][i];
            v = (t0 + n * 16 + la > row) ? -1e30f : v;
            s[n][i] = v;
            mx = fmaxf(mx, v);
          }
          mx = fmaxf(mx, __shfl_xor(mx, 1, 64));
          mx = fmaxf(mx, __shfl_xor(mx, 2, 64));
          mx = fmaxf(mx, __shfl_xor(mx, 4, 64));
          mx = fmaxf(mx, __shfl_xor(mx, 8, 64));
          mxr[i] = mx;
          need = fmaxf(need, mx - mrow[i]);
        }
        const bool resc = __any(need > 8.0f);
        float scalef[4];
        if (resc) {
#pragma unroll
          for (int i = 0; i < 4; ++i) {
            const float mnew = fmaxf(mrow[i], mxr[i]);
            scalef[i] = __expf(mrow[i] - mnew);
            mrow[i] = mnew;
          }
        }
        // pass 2: exp + row sum
#pragma unroll
        for (int i = 0; i < 4; ++i) {
          float ps = 0.f;
#pragma unroll
          for (int n = 0; n < 4; ++n) {
            float v = s[n][i];
            float pp = (v <= -1e29f) ? 0.f : __expf(v - mrow[i]);
            s[n][i] = pp;
            ps += pp;
          }
          ps += __shfl_xor(ps, 1, 64);
          ps += __shfl_xor(ps, 2, 64);
          ps += __shfl_xor(ps, 4, 64);
          ps += __shfl_xor(ps, 8, 64);
          lrow[i] = resc ? (lrow[i] * scalef[i] + ps) : (lrow[i] + ps);
        }
        if (resc) {
#pragma unroll
          for (int n = 0; n < 16; ++n) {
            acc[n][0] *= scalef[0]; acc[n][1] *= scalef[1];
            acc[n][2] *= scalef[2]; acc[n][3] *= scalef[3];
          }
        }
        bf16* pw = Ps + w * 1152;
#pragma unroll
        for (int n = 0; n < 4; ++n)
#pragma unroll
          for (int i = 0; i < 4; ++i)
            pw[(lq * 4 + i) * 72 + n * 16 + la] = (bf16)s[n][i];
        __builtin_amdgcn_s_setprio(1);
#pragma unroll
        for (int kc = 0; kc < 2; ++kc) {
          bf16x8 pa = *(const bf16x8*)(pw + la * 72 + kc * 32 + lq * 8);
#pragma unroll
          for (int n = 0; n < 16; ++n) {
            int rd = n * 16 + la;
            int sl = (kc * 4 + lq) ^ (rd & 7);
            bf16x8 vbv = *(const bf16x8*)(Vc + rd * 64 + sl * 8);
            acc[n] = __builtin_amdgcn_mfma_f32_16x16x32_bf16(pa, vbv, acc[n], 0, 0, 0);
          }
        }
        __builtin_amdgcn_s_setprio(0);
      }
      __builtin_amdgcn_s_barrier();
      __builtin_amdgcn_sched_barrier(0);
      cur ^= 1;
    }
#pragma unroll
    for (int i = 0; i < 4; ++i) {
      const int row = rbase + lq * 4 + i;
      const float inv = 1.0f / lrow[i];
      bf16* orow = o + ((size_t)(b * 2048 + row)) * 4096 + h * 256;
#pragma unroll
      for (int n = 0; n < 16; ++n) orow[n * 16 + la] = (bf16)(acc[n][i] * inv);
    }
  }
#undef STAGE
}

// ---------------- diagnostic fill if ws too small ----------------
__global__ void fill_err(float* o, int n) {
  int i = blockIdx.x * 256 + threadIdx.x;
  if (i < n) o[i] = 1e9f;
}

extern "C" void kernel_launch(void* const* d_in, const int* in_sizes, int n_in,
                              void* d_out, int out_size, void* d_ws, size_t ws_size,
                              hipStream_t stream) {
  const float* x = (const float*)d_in[0];
  const float* Wq = (const float*)d_in[1];
  const float* Wk = (const float*)d_in[2];
  const float* Wv = (const float*)d_in[3];
  const float* Wo = (const float*)d_in[4];
  const float* kscale = (const float*)d_in[5];
  const float* vscale = (const float*)d_in[6];
  const int* pos = (const int*)d_in[8];
  float* out = (float*)d_out;

  const size_t WS_NEED = 251658240ull;  // 240 MB
  if (ws_size < WS_NEED) {
    fill_err<<<65536, 256, 0, stream>>>(out, out_size);
    return;
  }
  char* ws = (char*)d_ws;
  bf16* x16   = (bf16*)(ws);                  // [4096][4096]   32 MB
  bf16* wqkvt = (bf16*)(ws + 33554432);       // [8192][4096]   64 MB (Q|K|V rows)
  bf16* wot   = (bf16*)(ws + 100663296);      // [4096][4096]   32 MB
  bf16* qkv   = (bf16*)(ws + 134217728);      // [4096][8192]   64 MB (Q|K|V cols)
  bf16* vtb   = (bf16*)(ws + 201326592);      // [2][8][256][2048] 16 MB
  bf16* ao    = (bf16*)(ws + 218103808);      // [4096][4096]   32 MB

  // prep: bf16 conversions + weight transposes (concatenated along N)
  cvt_bf16<<<16384, 256, 0, stream>>>(x, x16, 4194304);
  tconv<<<dim3(64, 64), 256, 0, stream>>>(Wq, wqkvt, 4096, 4096);
  tconv<<<dim3(32, 64), 256, 0, stream>>>(Wk, wqkvt + (size_t)4096 * 4096, 4096, 2048);
  tconv<<<dim3(32, 64), 256, 0, stream>>>(Wv, wqkvt + (size_t)6144 * 4096, 4096, 2048);
  tconv<<<dim3(64, 64), 256, 0, stream>>>(Wo, wot, 4096, 4096);

  // fused QKV projection: [4096][8192] = x16 @ wqkvt^T
  // grid 512: 16x32 btiles; per-XCD chunk = 8 by x 8 bx (ncc_l=2, cbx_l=3)
  gemm256<0><<<512, 512, 0, stream>>>(x16, wqkvt, qkv, 8192, 4096, 2, 3);

  // norms + rope on fused layout (q pre-scaled by 1/sqrt(HD))
  rope_q<<<16384, 256, 0, stream>>>(qkv, pos);
  norm_rope_k<<<8192, 256, 0, stream>>>(qkv + 4096, kscale, pos);
  norm_v<<<8192, 256, 0, stream>>>(qkv + 6144, vscale);
  vtrans<<<dim3(32, 4, 16), 256, 0, stream>>>(qkv + 6144, vtb);

  // attention: paired-qb load-balanced grid (256 blocks = 1/CU)
  flash_attn<<<dim3(16, 8, 2), 512, 0, stream>>>(qkv, vtb, ao);

  // output projection (fp32 out): grid 256: 16x16 btiles; chunk = 8 by x 4 bx
  gemm256<1><<<256, 512, 0, stream>>>(ao, wot, out, 4096, 4096, 2, 2);
}

// Round 17
// 611.269 us; speedup vs baseline: 1.0229x; 1.0194x over previous
//
#include <hip/hip_runtime.h>
#include <stdint.h>

typedef __bf16 bf16;
typedef __bf16 bf16x4 __attribute__((ext_vector_type(4)));
typedef __bf16 bf16x8 __attribute__((ext_vector_type(8)));
typedef float f32x4 __attribute__((ext_vector_type(4)));

#define GAS __attribute__((address_space(1)))
#define LAS __attribute__((address_space(3)))

__device__ __forceinline__ void gload_lds16(const void* g, void* l) {
  __builtin_amdgcn_global_load_lds((GAS const void*)g, (LAS void*)l, 16, 0, 0);
}

// ---------------- fp32 -> bf16 convert (x) ----------------
__global__ __launch_bounds__(256) void cvt_bf16(const float* __restrict__ in,
                                                bf16* __restrict__ out, int n4) {
  int i = blockIdx.x * 256 + threadIdx.x;
  if (i >= n4) return;
  float4 v = ((const float4*)in)[i];
  bf16x4 o;
  o[0] = (bf16)v.x; o[1] = (bf16)v.y; o[2] = (bf16)v.z; o[3] = (bf16)v.w;
  ((bf16x4*)out)[i] = o;
}

// ------------- W[K][N] f32 -> Wt[N][K] bf16 (transpose+convert) -------------
// Vectorized: float2 reads (8B/lane), bf16x4 writes (8B/lane, coalesced).
__global__ __launch_bounds__(256) void tconv(const float* __restrict__ W,
                                             bf16* __restrict__ Wt, int K, int N) {
  __shared__ bf16 tile[64][68];
  const int n0 = blockIdx.x * 64, k0 = blockIdx.y * 64;
  const int u2 = threadIdx.x & 31, kr0 = threadIdx.x >> 5;  // 32 n-pairs x 8 k-rows
#pragma unroll
  for (int i = 0; i < 8; ++i) {
    int kr = kr0 + i * 8;
    float2 v = *(const float2*)&W[(size_t)(k0 + kr) * N + n0 + u2 * 2];
    tile[kr][u2 * 2] = (bf16)v.x;
    tile[kr][u2 * 2 + 1] = (bf16)v.y;
  }
  __syncthreads();
  const int u4 = threadIdx.x & 15, nr0 = threadIdx.x >> 4;  // 16 k-quads x 16 n-rows
#pragma unroll
  for (int i = 0; i < 4; ++i) {
    int nr = nr0 + i * 16;
    bf16x4 o;
#pragma unroll
    for (int j = 0; j < 4; ++j) o[j] = tile[u4 * 4 + j][nr];
    *(bf16x4*)&Wt[(size_t)(n0 + nr) * K + k0 + u4 * 4] = o;
  }
}

// ============ 256x256 bf16 GEMM, depth-3 half-tile pipeline ============
// BK=64 processed as 2 kh-halves; LDS = 4 half-buffers[A 8192 | B 8192] =128KB.
// Half H uses buf H&3; its loads were issued 3 halves (~930cy) earlier ->
// covers HBM latency (~900cy). Steady state: 12 loads in flight, vmcnt(8)
// per boundary (retire current half's 4), 1 barrier per half.
// Slot swizzle sp = kl ^ ((row>>1)&3). 2D XCD chunking.
// Depth ladder measured: depth1.5=50%, depth3=52.8%, depth4=49.1% MfmaUtil ->
// depth-3 with compile-time buffer indices is the optimum of this family.
template <int OUTF32>
__global__ __launch_bounds__(512, 2) void gemm256(const bf16* __restrict__ A,
                                                  const bf16* __restrict__ Bt,
                                                  void* __restrict__ Cp,
                                                  const int N, const int K,
                                                  const int ncc_l, const int cbx_l) {
  __shared__ __attribute__((aligned(16))) bf16 lds[4][2][8192];
  const int t = threadIdx.x, w = t >> 6, l = t & 63;
  const int la = l & 15, lq = l >> 4;
  const int xcd = blockIdx.x & 7, wi = blockIdx.x >> 3;
  const int cr = xcd >> ncc_l, cc = xcd & ((1 << ncc_l) - 1);
  const int by = (cr << 3) + (wi >> cbx_l);
  const int bx = (cc << cbx_l) + (wi & ((1 << cbx_l) - 1));
  const int m0 = by * 256, n0 = bx * 256;
  const int wr = w >> 2, wc = w & 3;
  const int c0 = w * 64 + l;
  const int sr0 = c0 >> 2, soff = (((c0 & 3) ^ ((c0 >> 3) & 3)) << 3);
  const bf16* pA0 = A + (size_t)(m0 + sr0) * K + soff;
  const bf16* pA1 = pA0 + (size_t)128 * K;
  const bf16* pB0 = Bt + (size_t)(n0 + sr0) * K + soff;
  const bf16* pB1 = pB0 + (size_t)128 * K;
  const int rsl = (lq ^ ((la >> 1) & 3)) << 3;

  f32x4 acc[8][4] = {};

#define STAGE_A(b_, H_)                                                       \
  do {                                                                        \
    gload_lds16(pA0 + (H_) * 32, &lds[b_][0][w * 512]);                       \
    gload_lds16(pA1 + (H_) * 32, &lds[b_][0][4096 + w * 512]);                \
  } while (0)
#define STAGE_B(b_, H_)                                                       \
  do {                                                                        \
    gload_lds16(pB0 + (H_) * 32, &lds[b_][1][w * 512]);                       \
    gload_lds16(pB1 + (H_) * 32, &lds[b_][1][4096 + w * 512]);                \
  } while (0)

#define LOAD_BFR(b_)                                                          \
  _Pragma("unroll") for (int n_ = 0; n_ < 4; ++n_)                            \
      bfr[n_] = *(const bf16x8*)&lds[b_][1][(wc * 64 + n_ * 16 + la) * 32 + rsl];

#define PHASE(b_, mg)                                                         \
  {                                                                           \
    bf16x8 a_[4];                                                             \
    _Pragma("unroll") for (int m_ = 0; m_ < 4; ++m_)                          \
        a_[m_] = *(const bf16x8*)&lds[b_][0][(wr * 128 + (mg)*64 + m_ * 16 + la) * 32 + rsl]; \
    __builtin_amdgcn_s_setprio(1);                                            \
    _Pragma("unroll") for (int m_ = 0; m_ < 4; ++m_)                          \
      _Pragma("unroll") for (int n_ = 0; n_ < 4; ++n_)                        \
          acc[(mg)*4 + m_][n_] = __builtin_amdgcn_mfma_f32_16x16x32_bf16(     \
              a_[m_], bfr[n_], acc[(mg)*4 + m_][n_], 0, 0, 0);                \
    __builtin_amdgcn_s_setprio(0);                                            \
  }

  // prologue: stage halves 0..2 into bufs 0..2 (12 loads in flight)
  STAGE_A(0, 0); STAGE_B(0, 0);
  STAGE_A(1, 1); STAGE_B(1, 1);
  STAGE_A(2, 2); STAGE_B(2, 2);

  const int NH = K >> 5;  // 32-wide kh-halves
  for (int H = 0; H <= NH - 4; ++H) {
    const int b = H & 3, nb = (H + 3) & 3;
    bf16x8 bfr[4];
    asm volatile("s_waitcnt vmcnt(8)" ::: "memory");  // half H landed; H+1,H+2 fly
    __builtin_amdgcn_s_barrier();
    __builtin_amdgcn_sched_barrier(0);
    STAGE_A(nb, H + 3);
    LOAD_BFR(b)
    PHASE(b, 0)
    STAGE_B(nb, H + 3);
    PHASE(b, 1)
  }
  {  // H = NH-3: no more staging; outstanding 12 -> retire this half
    const int b = (NH - 3) & 3;
    bf16x8 bfr[4];
    asm volatile("s_waitcnt vmcnt(8)" ::: "memory");
    __builtin_amdgcn_s_barrier();
    __builtin_amdgcn_sched_barrier(0);
    LOAD_BFR(b)
    PHASE(b, 0)
    PHASE(b, 1)
  }
  {  // H = NH-2
    const int b = (NH - 2) & 3;
    bf16x8 bfr[4];
    asm volatile("s_waitcnt vmcnt(4)" ::: "memory");
    __builtin_amdgcn_s_barrier();
    __builtin_amdgcn_sched_barrier(0);
    LOAD_BFR(b)
    PHASE(b, 0)
    PHASE(b, 1)
  }
  {  // H = NH-1
    const int b = (NH - 1) & 3;
    bf16x8 bfr[4];
    asm volatile("s_waitcnt vmcnt(0)" ::: "memory");
    __builtin_amdgcn_s_barrier();
    __builtin_amdgcn_sched_barrier(0);
    LOAD_BFR(b)
    PHASE(b, 0)
    PHASE(b, 1)
  }
#undef PHASE
#undef LOAD_BFR
#undef STAGE_B
#undef STAGE_A

  const int crow = m0 + wr * 128, ccol = n0 + wc * 64;
  if (OUTF32) {
    float* C = (float*)Cp;
#pragma unroll
    for (int mi = 0; mi < 8; ++mi)
#pragma unroll
      for (int ni = 0; ni < 4; ++ni)
#pragma unroll
        for (int i = 0; i < 4; ++i)
          C[(size_t)(crow + mi * 16 + lq * 4 + i) * N + ccol + ni * 16 + la] = acc[mi][ni][i];
  } else {
    bf16* C = (bf16*)Cp;
#pragma unroll
    for (int mi = 0; mi < 8; ++mi)
#pragma unroll
      for (int ni = 0; ni < 4; ++ni)
#pragma unroll
        for (int i = 0; i < 4; ++i)
          C[(size_t)(crow + mi * 16 + lq * 4 + i) * N + ccol + ni * 16 + la] = (bf16)acc[mi][ni][i];
  }
}

// ------- Fused RoPE: q (blocks <16384, folds 1/sqrt(HD)) and k (RMSNorm+RoPE) -------
__global__ __launch_bounds__(256) void rope_qk(bf16* __restrict__ qkv,
                                               const float* __restrict__ kscale,
                                               const int* __restrict__ pos) {
  const int w = threadIdx.x >> 6, l = threadIdx.x & 63;
  if (blockIdx.x < 16384) {
    // ---- q: RoPE + fold 1/sqrt(HD) ----
    const int idx = blockIdx.x * 4 + w;
    const int bt = idx >> 4, h = idx & 15;  // HQ=16
    bf16* p = qkv + (size_t)bt * 8192 + h * 256 + l * 4;
    bf16x4 xv = *(const bf16x4*)p;
    float x[4], y[4];
#pragma unroll
    for (int j = 0; j < 4; ++j) x[j] = (float)xv[j];
#pragma unroll
    for (int j = 0; j < 4; ++j) y[j] = __shfl_xor(x[j], 32, 64);
    const float posf = (float)pos[bt];
    bf16x4 ov;
#pragma unroll
    for (int j = 0; j < 4; ++j) {
      const int pr = (l & 31) * 4 + j;  // pair index 0..127
      float sv, cv;
      sincosf(posf * exp2f((float)pr * (-13.287712379549449f / 128.0f)), &sv, &cv);
      float o = x[j] * cv + ((l < 32) ? -y[j] : y[j]) * sv;
      ov[j] = (bf16)(o * 0.0625f);  // 1/sqrt(256), exact pow2
    }
    *(bf16x4*)p = ov;
  } else {
    // ---- k: RMSNorm + RoPE (fused qkv +4096) ----
    const int idx = (blockIdx.x - 16384) * 4 + w;
    const int bt = idx >> 3, h = idx & 7;  // HKV=8
    bf16* p = qkv + 4096 + (size_t)bt * 8192 + h * 256 + l * 4;
    bf16x4 xv = *(const bf16x4*)p;
    float x[4];
#pragma unroll
    for (int j = 0; j < 4; ++j) x[j] = (float)xv[j];
    float ss = x[0] * x[0] + x[1] * x[1] + x[2] * x[2] + x[3] * x[3];
#pragma unroll
    for (int m = 1; m < 64; m <<= 1) ss += __shfl_xor(ss, m, 64);
    const float r = rsqrtf(ss * (1.0f / 256.0f) + 1e-6f);
#pragma unroll
    for (int j = 0; j < 4; ++j) x[j] = x[j] * r * (1.0f + kscale[l * 4 + j]);
    float y[4];
#pragma unroll
    for (int j = 0; j < 4; ++j) y[j] = __shfl_xor(x[j], 32, 64);
    const float posf = (float)pos[bt];
    bf16x4 ov;
#pragma unroll
    for (int j = 0; j < 4; ++j) {
      const int pr = (l & 31) * 4 + j;
      float sv, cv;
      sincosf(posf * exp2f((float)pr * (-13.287712379549449f / 128.0f)), &sv, &cv);
      float o = x[j] * cv + ((l < 32) ? -y[j] : y[j]) * sv;
      ov[j] = (bf16)o;
    }
    *(bf16x4*)p = ov;
  }
}

// ---- Fused RMSNorm(v) + transpose: qkv v-region -> vt [b,hkv,d,t] ----
// Eliminates the intermediate 16 MB write + 16 MB re-read of the separate
// norm_v / vtrans pair. Block = (t-tile of 64, bh); LDS [64 t][260 d pad].
__global__ __launch_bounds__(256) void normv_trans(const bf16* __restrict__ vbase,
                                                   const float* __restrict__ scale,
                                                   bf16* __restrict__ vt) {
  __shared__ bf16 tile[64][260];
  const int tt = blockIdx.x, bh = blockIdx.y;
  const int b = bh >> 3, h = bh & 7;
  const int w = threadIdx.x >> 6, l = threadIdx.x & 63;
  // phase 1: load 64 rows (4 waves x 16), RMSNorm per row, write LDS row-major
#pragma unroll
  for (int it = 0; it < 16; ++it) {
    const int tr = it * 4 + w;
    const bf16* p = vbase + (size_t)(b * 2048 + tt * 64 + tr) * 8192 + h * 256 + l * 4;
    bf16x4 xv = *(const bf16x4*)p;
    float x[4];
#pragma unroll
    for (int j = 0; j < 4; ++j) x[j] = (float)xv[j];
    float ss = x[0] * x[0] + x[1] * x[1] + x[2] * x[2] + x[3] * x[3];
#pragma unroll
    for (int m = 1; m < 64; m <<= 1) ss += __shfl_xor(ss, m, 64);
    const float r = rsqrtf(ss * (1.0f / 256.0f) + 1e-6f);
    bf16x4 ov;
#pragma unroll
    for (int j = 0; j < 4; ++j) ov[j] = (bf16)(x[j] * r * (1.0f + scale[l * 4 + j]));
    *(bf16x4*)&tile[tr][l * 4] = ov;
  }
  __syncthreads();
  // phase 2: transposed write-out, bf16x4 over t (coalesced 128B segments)
  const int u4 = threadIdx.x & 15, r0 = threadIdx.x >> 4;
#pragma unroll
  for (int it = 0; it < 16; ++it) {
    const int dr = it * 16 + r0;
    bf16x4 o;
#pragma unroll
    for (int j = 0; j < 4; ++j) o[j] = tile[u4 * 4 + j][dr];
    *(bf16x4*)&vt[((size_t)(b * 8 + h) * 256 + dr) * 2048 + tt * 64 + u4 * 4] = o;
  }
}

// ---------------- flash attention (causal, GQA group=2) ----------------
// block = (h, qbp, b): processes qb pair {15-qbp, qbp} (34 K/V tiles each,
// 256 blocks = 1/CU). K read from fused qkv (row stride 8192).
// T13 defer-max: skip O-rescale + m-update when tile max grows < 8.
__global__ __launch_bounds__(512, 2) void flash_attn(const bf16* __restrict__ qkv,
                                                     const bf16* __restrict__ vt,
                                                     bf16* __restrict__ o) {
  __shared__ __attribute__((aligned(16))) bf16 Ks[2 * 16384];
  __shared__ __attribute__((aligned(16))) bf16 Vs[2 * 16384];
  __shared__ __attribute__((aligned(16))) bf16 Ps[8 * 1152];  // per-wave [16][72]
  const int t = threadIdx.x, w = t >> 6, l = t & 63;
  const int la = l & 15, lq = l >> 4;
  const int h = blockIdx.x, qbp = blockIdx.y, b = blockIdx.z;
  const int hkv = h >> 1;

  const bf16* kbase = qkv + (size_t)(b * 2048) * 8192 + 4096 + hkv * 256;
  const bf16* vbase = vt + ((size_t)(b * 8 + hkv)) * 256 * 2048;

  const bf16* ksrc[4];
  const bf16* vsrc[4];
#pragma unroll
  for (int i = 0; i < 4; ++i) {
    int c = i * 512 + t;
    int krr = c >> 5, ksl = (c & 31) ^ (krr & 7);
    int vrr = c >> 3, vsl = (c & 7) ^ (vrr & 7);
    ksrc[i] = kbase + (size_t)krr * 8192 + ksl * 8;
    vsrc[i] = vbase + (size_t)vrr * 2048 + vsl * 8;
  }

#define STAGE(bb, tt0)                                                        \
  do {                                                                        \
    _Pragma("unroll") for (int i_ = 0; i_ < 4; ++i_)                          \
        gload_lds16(ksrc[i_] + (size_t)(tt0) * 8192,                          \
                    Ks + (bb) * 16384 + i_ * 4096 + w * 512);                 \
    _Pragma("unroll") for (int i_ = 0; i_ < 4; ++i_)                          \
        gload_lds16(vsrc[i_] + (tt0), Vs + (bb) * 16384 + i_ * 4096 + w * 512); \
  } while (0)

  for (int part = 0; part < 2; ++part) {
    const int qb = part ? qbp : (15 - qbp);
    const int q0 = qb * 128;
    const int rbase = q0 + w * 16;

    bf16x8 qf[8];
    {
      const bf16* qrow = qkv + (size_t)(b * 2048 + rbase + la) * 8192 + h * 256 + lq * 8;
#pragma unroll
      for (int kg = 0; kg < 8; ++kg) qf[kg] = *(const bf16x8*)(qrow + kg * 32);
    }
    f32x4 acc[16] = {};
    float mrow[4] = {-1e30f, -1e30f, -1e30f, -1e30f};
    float lrow[4] = {0.f, 0.f, 0.f, 0.f};
    const int nT = 2 * qb + 2;

    STAGE(0, 0);
    int cur = 0;
    for (int tti = 0; tti < nT; ++tti) {
      const int t0 = tti * 64;
      if (tti + 1 < nT) {
        STAGE(cur ^ 1, t0 + 64);
        asm volatile("s_waitcnt vmcnt(8)" ::: "memory");  // cur landed, next flies
      } else {
        asm volatile("s_waitcnt vmcnt(0)" ::: "memory");
      }
      __builtin_amdgcn_s_barrier();
      __builtin_amdgcn_sched_barrier(0);
      if (t0 <= rbase + 15) {
        const bf16* Kc = Ks + cur * 16384;
        const bf16* Vc = Vs + cur * 16384;
        f32x4 s[4] = {};
        __builtin_amdgcn_s_setprio(1);
#pragma unroll
        for (int n = 0; n < 4; ++n) {
          int rT = n * 16 + la;
#pragma unroll
          for (int kg = 0; kg < 8; ++kg) {
            int sl = (kg * 4 + lq) ^ (rT & 7);
            bf16x8 kbv = *(const bf16x8*)(Kc + rT * 256 + sl * 8);
            s[n] = __builtin_amdgcn_mfma_f32_16x16x32_bf16(qf[kg], kbv, s[n], 0, 0, 0);
          }
        }
        __builtin_amdgcn_s_setprio(0);
        // pass 1: causal mask + per-row tile max
        float mxr[4];
        float need = -1.f;
#pragma unroll
        for (int i = 0; i < 4; ++i) {
          const int row = rbase + lq * 4 + i;
          float mx = -1e30f;
#pragma unroll
          for (int n = 0; n < 4; ++n) {
            float v = s[n][i];
            v = (t0 + n * 16 + la > row) ? -1e30f : v;
            s[n][i] = v;
            mx = fmaxf(mx, v);
          }
          mx = fmaxf(mx, __shfl_xor(mx, 1, 64));
          mx = fmaxf(mx, __shfl_xor(mx, 2, 64));
          mx = fmaxf(mx, __shfl_xor(mx, 4, 64));
          mx = fmaxf(mx, __shfl_xor(mx, 8, 64));
          mxr[i] = mx;
          need = fmaxf(need, mx - mrow[i]);
        }
        const bool resc = __any(need > 8.0f);
        float scalef[4];
        if (resc) {
#pragma unroll
          for (int i = 0; i < 4; ++i) {
            const float mnew = fmaxf(mrow[i], mxr[i]);
            scalef[i] = __expf(mrow[i] - mnew);
            mrow[i] = mnew;
          }
        }
        // pass 2: exp + row sum
#pragma unroll
        for (int i = 0; i < 4; ++i) {
          float ps = 0.f;
#pragma unroll
          for (int n = 0; n < 4; ++n) {
            float v = s[n][i];
            float pp = (v <= -1e29f) ? 0.f : __expf(v - mrow[i]);
            s[n][i] = pp;
            ps += pp;
          }
          ps += __shfl_xor(ps, 1, 64);
          ps += __shfl_xor(ps, 2, 64);
          ps += __shfl_xor(ps, 4, 64);
          ps += __shfl_xor(ps, 8, 64);
          lrow[i] = resc ? (lrow[i] * scalef[i] + ps) : (lrow[i] + ps);
        }
        if (resc) {
#pragma unroll
          for (int n = 0; n < 16; ++n) {
            acc[n][0] *= scalef[0]; acc[n][1] *= scalef[1];
            acc[n][2] *= scalef[2]; acc[n][3] *= scalef[3];
          }
        }
        bf16* pw = Ps + w * 1152;
#pragma unroll
        for (int n = 0; n < 4; ++n)
#pragma unroll
          for (int i = 0; i < 4; ++i)
            pw[(lq * 4 + i) * 72 + n * 16 + la] = (bf16)s[n][i];
        __builtin_amdgcn_s_setprio(1);
#pragma unroll
        for (int kc = 0; kc < 2; ++kc) {
          bf16x8 pa = *(const bf16x8*)(pw + la * 72 + kc * 32 + lq * 8);
#pragma unroll
          for (int n = 0; n < 16; ++n) {
            int rd = n * 16 + la;
            int sl = (kc * 4 + lq) ^ (rd & 7);
            bf16x8 vbv = *(const bf16x8*)(Vc + rd * 64 + sl * 8);
            acc[n] = __builtin_amdgcn_mfma_f32_16x16x32_bf16(pa, vbv, acc[n], 0, 0, 0);
          }
        }
        __builtin_amdgcn_s_setprio(0);
      }
      __builtin_amdgcn_s_barrier();
      __builtin_amdgcn_sched_barrier(0);
      cur ^= 1;
    }
#pragma unroll
    for (int i = 0; i < 4; ++i) {
      const int row = rbase + lq * 4 + i;
      const float inv = 1.0f / lrow[i];
      bf16* orow = o + ((size_t)(b * 2048 + row)) * 4096 + h * 256;
#pragma unroll
      for (int n = 0; n < 16; ++n) orow[n * 16 + la] = (bf16)(acc[n][i] * inv);
    }
  }
#undef STAGE
}

// ---------------- diagnostic fill if ws too small ----------------
__global__ void fill_err(float* o, int n) {
  int i = blockIdx.x * 256 + threadIdx.x;
  if (i < n) o[i] = 1e9f;
}

extern "C" void kernel_launch(void* const* d_in, const int* in_sizes, int n_in,
                              void* d_out, int out_size, void* d_ws, size_t ws_size,
                              hipStream_t stream) {
  const float* x = (const float*)d_in[0];
  const float* Wq = (const float*)d_in[1];
  const float* Wk = (const float*)d_in[2];
  const float* Wv = (const float*)d_in[3];
  const float* Wo = (const float*)d_in[4];
  const float* kscale = (const float*)d_in[5];
  const float* vscale = (const float*)d_in[6];
  const int* pos = (const int*)d_in[8];
  float* out = (float*)d_out;

  const size_t WS_NEED = 251658240ull;  // 240 MB
  if (ws_size < WS_NEED) {
    fill_err<<<65536, 256, 0, stream>>>(out, out_size);
    return;
  }
  char* ws = (char*)d_ws;
  bf16* x16   = (bf16*)(ws);                  // [4096][4096]   32 MB
  bf16* wqkvt = (bf16*)(ws + 33554432);       // [8192][4096]   64 MB (Q|K|V rows)
  bf16* wot   = (bf16*)(ws + 100663296);      // [4096][4096]   32 MB
  bf16* qkv   = (bf16*)(ws + 134217728);      // [4096][8192]   64 MB (Q|K|V cols)
  bf16* vtb   = (bf16*)(ws + 201326592);      // [2][8][256][2048] 16 MB
  bf16* ao    = (bf16*)(ws + 218103808);      // [4096][4096]   32 MB

  // prep: bf16 conversions + weight transposes (concatenated along N)
  cvt_bf16<<<16384, 256, 0, stream>>>(x, x16, 4194304);
  tconv<<<dim3(64, 64), 256, 0, stream>>>(Wq, wqkvt, 4096, 4096);
  tconv<<<dim3(32, 64), 256, 0, stream>>>(Wk, wqkvt + (size_t)4096 * 4096, 4096, 2048);
  tconv<<<dim3(32, 64), 256, 0, stream>>>(Wv, wqkvt + (size_t)6144 * 4096, 4096, 2048);
  tconv<<<dim3(64, 64), 256, 0, stream>>>(Wo, wot, 4096, 4096);

  // fused QKV projection: [4096][8192] = x16 @ wqkvt^T
  // grid 512: 16x32 btiles; per-XCD chunk = 8 by x 8 bx (ncc_l=2, cbx_l=3)
  gemm256<0><<<512, 512, 0, stream>>>(x16, wqkvt, qkv, 8192, 4096, 2, 3);

  // fused rope(q)+rmsnorm/rope(k); fused rmsnorm(v)+transpose
  rope_qk<<<24576, 256, 0, stream>>>(qkv, kscale, pos);
  normv_trans<<<dim3(32, 16), 256, 0, stream>>>(qkv + 6144, vscale, vtb);

  // attention: paired-qb load-balanced grid (256 blocks = 1/CU)
  flash_attn<<<dim3(16, 8, 2), 512, 0, stream>>>(qkv, vtb, ao);

  // output projection (fp32 out): grid 256: 16x16 btiles; chunk = 8 by x 4 bx
  gemm256<1><<<256, 512, 0, stream>>>(ao, wot, out, 4096, 4096, 2, 2);
}